// Round 1
// baseline (530.148 us; speedup 1.0000x reference)
//
#include <hip/hip_runtime.h>
#include <hip/hip_bf16.h>

#define T_ 2048
#define N_ 1024
#define D_ 64
#define NCH 16     // attention n-chunks
#define ACH 64     // n per chunk

typedef __bf16 bf16x8 __attribute__((ext_vector_type(8)));
typedef float f32x4 __attribute__((ext_vector_type(4)));

__device__ __forceinline__ float fast_erf(float x) {
    // Abramowitz & Stegun 7.1.26, |eps| <= 1.5e-7
    float a = fabsf(x);
    float t = __builtin_amdgcn_rcpf(1.0f + 0.3275911f * a);
    float p = t * (0.254829592f + t * (-0.284496736f + t * (1.421413741f +
              t * (-1.453152027f + t * 1.061405429f))));
    float e = __expf(-a * a);
    float r = 1.0f - p * e;
    return copysignf(r, x);
}
__device__ __forceinline__ float gelu_f(float x) {
    return 0.5f * x * (1.0f + fast_erf(x * 0.7071067811865476f));
}

// ---------------- query embedding: z = gelu(inp@W1^T+b1)@W2^T+b2 ----------------
__global__ void qe_kernel(const float* __restrict__ qpts, const float* __restrict__ W1,
                          const float* __restrict__ b1, const float* __restrict__ W2,
                          const float* __restrict__ b2, float* __restrict__ z) {
    int t = blockIdx.x, l = threadIdx.x;
    __shared__ float inp[51];
    __shared__ float h[64];
    float q0 = qpts[t*3+0], q1 = qpts[t*3+1], q2 = qpts[t*3+2];
    if (l < 3) inp[l] = (l==0?q0:(l==1?q1:q2));
    if (l < 48) {
        int i = l >> 4, r = l & 15, f = r & 7;
        float qv = (i==0?q0:(i==1?q1:q2));
        float ang = qv * ((float)(1<<f) * 3.14159265358979323846f);
        inp[3+l] = (r < 8) ? sinf(ang) : cosf(ang);
    }
    __syncthreads();
    float s = b1[l];
    #pragma unroll
    for (int j = 0; j < 51; ++j) s += inp[j] * W1[l*51+j];
    h[l] = gelu_f(s);
    __syncthreads();
    float s2 = b2[l];
    #pragma unroll
    for (int k = 0; k < 64; ++k) s2 += h[k] * W2[l*64+k];
    z[t*64+l] = s2;
}

// ---------------- q/k/v projections (block<T: q row; else k,v row) ----------------
__global__ void proj_kernel(const float* __restrict__ z, const float* __restrict__ H,
                            const float* __restrict__ w,
                            float* __restrict__ q, float* __restrict__ kb,
                            float* __restrict__ vb) {
    int b = blockIdx.x, l = threadIdx.x;
    __shared__ float r[64];
    if (b < T_) {
        r[l] = z[b*64+l];
        __syncthreads();
        float s = 0.f;
        #pragma unroll
        for (int j = 0; j < 64; ++j) s += r[j] * w[l*64+j];
        q[b*64+l] = s;
    } else {
        int n = b - T_;
        r[l] = H[n*64+l];
        __syncthreads();
        float sk = 0.f, sv = 0.f;
        #pragma unroll
        for (int j = 0; j < 64; ++j) {
            float hv = r[j];
            sk += hv * w[(64+l)*64+j];
            sv += hv * w[(128+l)*64+j];
        }
        kb[n*64+l] = sk;
        vb[n*64+l] = sv;
    }
}

// ---------------- attention partials: lane = t, wave-uniform K/V broadcast ----------------
// scores are tiny (|s|<~16) => exp without max subtraction is safe & matches softmax exactly
__global__ void attn_part_kernel(const float* __restrict__ q, const float* __restrict__ kb,
                                 const float* __restrict__ vb,
                                 float* __restrict__ ps, float* __restrict__ pa) {
    int wid = blockIdx.x*4 + (threadIdx.x >> 6);
    int lane = threadIdx.x & 63;
    int c = wid & (NCH-1);
    int h = (wid >> 4) & 3;
    int tg = wid >> 6;
    int t = tg*64 + lane;
    float qv[16];
    #pragma unroll
    for (int d = 0; d < 16; ++d) qv[d] = q[t*64 + h*16 + d];
    float ssum = 0.f;
    float acc[16];
    #pragma unroll
    for (int d = 0; d < 16; ++d) acc[d] = 0.f;
    for (int i = 0; i < ACH; ++i) {
        int n = c*ACH + i;
        const float* kr = kb + n*64 + h*16;
        const float* vr = vb + n*64 + h*16;
        float s = 0.f;
        #pragma unroll
        for (int d = 0; d < 16; ++d) s += qv[d] * kr[d];
        float w = __expf(s * 0.25f);
        ssum += w;
        #pragma unroll
        for (int d = 0; d < 16; ++d) acc[d] += w * vr[d];
    }
    int idx = (h*NCH + c)*T_ + t;
    ps[idx] = ssum;
    #pragma unroll
    for (int d = 0; d < 16; ++d) pa[idx*16 + d] = acc[d];
}

// ---------------- combine partials + out-proj + residual + LN ----------------
__global__ void attn_fin_kernel(const float* __restrict__ ps, const float* __restrict__ pa,
                                const float* __restrict__ Wout, const float* __restrict__ z,
                                const float* __restrict__ g, const float* __restrict__ bt,
                                float* __restrict__ xout) {
    int t = blockIdx.x, l = threadIdx.x;
    int h = l >> 4, d = l & 15;
    __shared__ float osh[64];
    float stot = 0.f, atot = 0.f;
    #pragma unroll
    for (int c = 0; c < NCH; ++c) {
        int idx = (h*NCH + c)*T_ + t;
        stot += ps[idx];
        atot += pa[idx*16 + d];
    }
    osh[l] = atot / stot;
    __syncthreads();
    float s = 0.f;
    #pragma unroll
    for (int k = 0; k < 64; ++k) s += osh[k] * Wout[l*64+k];
    s += z[t*64+l];
    float s1 = s, s2 = s*s;
    #pragma unroll
    for (int m = 32; m >= 1; m >>= 1) { s1 += __shfl_xor(s1, m); s2 += __shfl_xor(s2, m); }
    float mean = s1 * (1.f/64.f);
    float var = s2 * (1.f/64.f) - mean*mean;
    xout[t*64+l] = (s - mean) * rsqrtf(var + 1e-5f) * g[l] + bt[l];
}

// ---------------- FFN + residual + LN ----------------
__global__ void ffn_kernel(const float* __restrict__ x, const float* __restrict__ W1,
                           const float* __restrict__ b1, const float* __restrict__ W2,
                           const float* __restrict__ b2, const float* __restrict__ g,
                           const float* __restrict__ bt, float* __restrict__ zout) {
    int t = blockIdx.x, j = threadIdx.x;
    __shared__ float xr[64];
    __shared__ float h[256];
    if (j < 64) xr[j] = x[t*64+j];
    __syncthreads();
    float s = b1[j];
    #pragma unroll
    for (int k = 0; k < 64; ++k) s += xr[k] * W1[j*64+k];
    h[j] = gelu_f(s);
    __syncthreads();
    if (j < 64) {
        float v = b2[j];
        #pragma unroll
        for (int k = 0; k < 256; ++k) v += h[k] * W2[j*256+k];
        v += xr[j];
        float s1 = v, s2 = v*v;
        #pragma unroll
        for (int m = 32; m >= 1; m >>= 1) { s1 += __shfl_xor(s1, m); s2 += __shfl_xor(s2, m); }
        float mean = s1 * (1.f/64.f);
        float var = s2 * (1.f/64.f) - mean*mean;
        zout[t*64+j] = (v - mean) * rsqrtf(var + 1e-5f) * g[j] + bt[j];
    }
}

// ---------------- az / aH projections for pair head ----------------
__global__ void azah_kernel(const float* __restrict__ z, const float* __restrict__ H,
                            const float* __restrict__ pw1,
                            float* __restrict__ az, float* __restrict__ aH) {
    int b = blockIdx.x, l = threadIdx.x;
    __shared__ float r[64];
    if (b < T_) {
        r[l] = z[b*64+l];
        __syncthreads();
        float s = 0.f;
        #pragma unroll
        for (int k = 0; k < 64; ++k) s += r[k] * pw1[l*128 + k];
        az[b*64+l] = s;
    } else {
        int n = b - T_;
        r[l] = H[n*64+l];
        __syncthreads();
        float s = 0.f;
        #pragma unroll
        for (int k = 0; k < 64; ++k) s += r[k] * pw1[l*128 + 64 + k];
        aH[n*64+l] = s;
    }
}

// ---------------- fused pairwise head ----------------
// wave handles (t, half of n-range); per 16-n tile: u=gelu(az+aH+b1) in MFMA-A layout,
// LN via shfl_xor(16,32), 64x64 GEMM via 8x mfma_f32_16x16x32_bf16, gelu, W3 via
// 16-lane shuffle reduction. C layout: col=lane&15, row=(lane>>4)*4+reg.
__global__ void pair_kernel(const float* __restrict__ az, const float* __restrict__ aH,
                            const float* __restrict__ b1, const float* __restrict__ lng,
                            const float* __restrict__ lnb, const float* __restrict__ W2,
                            const float* __restrict__ b2, const float* __restrict__ W3,
                            const float* __restrict__ b3, float* __restrict__ out) {
    int wid = blockIdx.x*4 + (threadIdx.x >> 6);   // 0..4095
    int lane = threadIdx.x & 63;
    int t = wid >> 1;
    int hlf = wid & 1;
    int cLo = lane & 15;   // A: pair row; B/C: col
    int kg = lane >> 4;    // k-group

    // B fragments of W2 (v_c = sum_k u_k * W2[c,k]  => B[k][c] = W2[c*64+k])
    bf16x8 bf[4][2];
    #pragma unroll
    for (int ct = 0; ct < 4; ++ct)
        #pragma unroll
        for (int kt = 0; kt < 2; ++kt) {
            int col = ct*16 + cLo;
            int kbs = kt*32 + kg*8;
            #pragma unroll
            for (int j = 0; j < 8; ++j)
                bf[ct][kt][j] = (__bf16)W2[col*64 + kbs + j];
        }
    float w3v[3][4], b2v[4], b3v[3];
    #pragma unroll
    for (int ct = 0; ct < 4; ++ct) {
        b2v[ct] = b2[ct*16 + cLo];
        #pragma unroll
        for (int j = 0; j < 3; ++j) w3v[j][ct] = W3[j*64 + ct*16 + cLo];
    }
    #pragma unroll
    for (int j = 0; j < 3; ++j) b3v[j] = b3[j];

    // per-lane dims: d = kt*32 + kg*8 + j
    float azv[16], b1v[16], gv[16], bv[16];
    #pragma unroll
    for (int kt = 0; kt < 2; ++kt)
        #pragma unroll
        for (int j = 0; j < 8; ++j) {
            int d = kt*32 + kg*8 + j;
            azv[kt*8+j] = az[t*64 + d];
            b1v[kt*8+j] = b1[d];
            gv[kt*8+j]  = lng[d];
            bv[kt*8+j]  = lnb[d];
        }

    for (int tile = hlf*32; tile < hlf*32 + 32; ++tile) {
        int n = tile*16 + cLo;
        float u[16];
        float s1 = 0.f, s2 = 0.f;
        #pragma unroll
        for (int kt = 0; kt < 2; ++kt)
            #pragma unroll
            for (int j = 0; j < 8; ++j) {
                int d = kt*32 + kg*8 + j;
                float val = azv[kt*8+j] + aH[n*64 + d] + b1v[kt*8+j];
                float uu = gelu_f(val);
                u[kt*8+j] = uu;
                s1 += uu;
                s2 += uu*uu;
            }
        s1 += __shfl_xor(s1, 16); s1 += __shfl_xor(s1, 32);
        s2 += __shfl_xor(s2, 16); s2 += __shfl_xor(s2, 32);
        float mean = s1 * (1.0f/64.0f);
        float var = s2 * (1.0f/64.0f) - mean*mean;
        float inv = rsqrtf(var + 1e-5f);

        bf16x8 af[2];
        #pragma unroll
        for (int kt = 0; kt < 2; ++kt)
            #pragma unroll
            for (int j = 0; j < 8; ++j)
                af[kt][j] = (__bf16)((u[kt*8+j] - mean) * inv * gv[kt*8+j] + bv[kt*8+j]);

        f32x4 acc[4];
        #pragma unroll
        for (int ct = 0; ct < 4; ++ct) acc[ct] = (f32x4){0.f,0.f,0.f,0.f};
        #pragma unroll
        for (int ct = 0; ct < 4; ++ct)
            #pragma unroll
            for (int kt = 0; kt < 2; ++kt)
                acc[ct] = __builtin_amdgcn_mfma_f32_16x16x32_bf16(af[kt], bf[ct][kt], acc[ct], 0, 0, 0);

        float pj[3][4];
        #pragma unroll
        for (int j = 0; j < 3; ++j)
            #pragma unroll
            for (int r = 0; r < 4; ++r) pj[j][r] = 0.f;
        #pragma unroll
        for (int ct = 0; ct < 4; ++ct)
            #pragma unroll
            for (int r = 0; r < 4; ++r) {
                float vg = gelu_f(acc[ct][r] + b2v[ct]);
                pj[0][r] += vg * w3v[0][ct];
                pj[1][r] += vg * w3v[1][ct];
                pj[2][r] += vg * w3v[2][ct];
            }
        #pragma unroll
        for (int j = 0; j < 3; ++j)
            #pragma unroll
            for (int r = 0; r < 4; ++r) {
                float v = pj[j][r];
                v += __shfl_xor(v, 1); v += __shfl_xor(v, 2);
                v += __shfl_xor(v, 4); v += __shfl_xor(v, 8);
                pj[j][r] = v;
            }
        if (cLo < 3) {
            int j = cLo;
            #pragma unroll
            for (int r = 0; r < 4; ++r) {
                int row = kg*4 + r;
                out[t*3072 + (tile*16 + row)*3 + j] = pj[j][r] + b3v[j];
            }
        }
    }
}

extern "C" void kernel_launch(void* const* d_in, const int* in_sizes, int n_in,
                              void* d_out, int out_size, void* d_ws, size_t ws_size,
                              hipStream_t stream) {
    const float* H         = (const float*)d_in[0];
    const float* qpts      = (const float*)d_in[1];
    const float* qe_W1     = (const float*)d_in[2];
    const float* qe_b1     = (const float*)d_in[3];
    const float* qe_W2     = (const float*)d_in[4];
    const float* qe_b2     = (const float*)d_in[5];
    const float* attn_in_w = (const float*)d_in[6];
    const float* attn_out_w= (const float*)d_in[7];
    const float* ln1_g     = (const float*)d_in[8];
    const float* ln1_b     = (const float*)d_in[9];
    const float* ffn_W1    = (const float*)d_in[10];
    const float* ffn_b1    = (const float*)d_in[11];
    const float* ffn_W2    = (const float*)d_in[12];
    const float* ffn_b2    = (const float*)d_in[13];
    const float* ln2_g     = (const float*)d_in[14];
    const float* ln2_b     = (const float*)d_in[15];
    const float* pm_W1     = (const float*)d_in[16];
    const float* pm_b1     = (const float*)d_in[17];
    const float* pm_ln_g   = (const float*)d_in[18];
    const float* pm_ln_b   = (const float*)d_in[19];
    const float* pm_W2     = (const float*)d_in[20];
    const float* pm_b2     = (const float*)d_in[21];
    const float* pm_W3     = (const float*)d_in[22];
    const float* pm_b3     = (const float*)d_in[23];

    float* ws = (float*)d_ws;
    float* z  = ws;            // 131072
    float* xb = ws + 131072;   // 131072
    float* q  = ws + 262144;   // 131072
    float* kb = ws + 393216;   // 65536
    float* vb = ws + 458752;   // 65536
    float* az = ws + 524288;   // 131072
    float* aH = ws + 655360;   // 65536
    float* ps = ws + 720896;   // 4*16*2048 = 131072
    float* pa = ws + 851968;   // 131072*16 = 2097152  (end 2949120 floats = 11.8 MB)
    float* out = (float*)d_out;

    qe_kernel<<<T_, 64, 0, stream>>>(qpts, qe_W1, qe_b1, qe_W2, qe_b2, z);
    for (int i = 0; i < 2; ++i) {
        proj_kernel<<<T_ + N_, 64, 0, stream>>>(z, H, attn_in_w + i*192*64, q, kb, vb);
        attn_part_kernel<<<512, 256, 0, stream>>>(q, kb, vb, ps, pa);
        attn_fin_kernel<<<T_, 64, 0, stream>>>(ps, pa, attn_out_w + i*64*64, z,
                                               ln1_g + i*64, ln1_b + i*64, xb);
        ffn_kernel<<<T_, 256, 0, stream>>>(xb, ffn_W1 + i*256*64, ffn_b1 + i*256,
                                           ffn_W2 + i*64*256, ffn_b2 + i*64,
                                           ln2_g + i*64, ln2_b + i*64, z);
    }
    azah_kernel<<<T_ + N_, 64, 0, stream>>>(z, H, pm_W1, az, aH);
    pair_kernel<<<1024, 256, 0, stream>>>(az, aH, pm_b1, pm_ln_g, pm_ln_b,
                                          pm_W2, pm_b2, pm_W3, pm_b3, out);
}

// Round 2
// 442.218 us; speedup vs baseline: 1.1988x; 1.1988x over previous
//
#include <hip/hip_runtime.h>
#include <hip/hip_bf16.h>

#define T_ 2048
#define N_ 1024
#define NCH 16

typedef __bf16 bf16x8 __attribute__((ext_vector_type(8)));
typedef float f32x4 __attribute__((ext_vector_type(4)));

__device__ __forceinline__ float fast_erf(float x) {
    // Abramowitz & Stegun 7.1.26, |eps| <= 1.5e-7
    float a = fabsf(x);
    float t = __builtin_amdgcn_rcpf(1.0f + 0.3275911f * a);
    float p = t * (0.254829592f + t * (-0.284496736f + t * (1.421413741f +
              t * (-1.453152027f + t * 1.061405429f))));
    float e = __expf(-a * a);
    float r = 1.0f - p * e;
    return copysignf(r, x);
}
__device__ __forceinline__ float gelu_f(float x) {
    return 0.5f * x * (1.0f + fast_erf(x * 0.7071067811865476f));
}

// ---------------- query embedding (4 t per block, 1 per wave) ----------------
__global__ void qe_kernel(const float* __restrict__ qpts, const float* __restrict__ W1,
                          const float* __restrict__ b1, const float* __restrict__ W2,
                          const float* __restrict__ b2, float* __restrict__ z) {
    int w = threadIdx.x >> 6, l = threadIdx.x & 63;
    int t = blockIdx.x * 4 + w;
    __shared__ float inp[4][52];
    __shared__ float h[4][64];
    float q0 = qpts[t*3+0], q1 = qpts[t*3+1], q2 = qpts[t*3+2];
    if (l < 3) inp[w][l] = (l==0?q0:(l==1?q1:q2));
    if (l < 48) {
        int i = l >> 4, r = l & 15, f = r & 7;
        float qv = (i==0?q0:(i==1?q1:q2));
        float ang = qv * ((float)(1<<f) * 3.14159265358979323846f);
        inp[w][3+l] = (r < 8) ? sinf(ang) : cosf(ang);
    }
    __syncthreads();
    float s = b1[l];
    #pragma unroll
    for (int j = 0; j < 51; ++j) s += inp[w][j] * W1[l*51+j];
    h[w][l] = gelu_f(s);
    __syncthreads();
    float s2 = b2[l];
    #pragma unroll
    for (int k = 0; k < 64; ++k) s2 += h[w][k] * W2[l*64+k];
    z[t*64+l] = s2;
}

// ---------------- q/k/v projections (4 rows per block) ----------------
__global__ void proj_kernel(const float* __restrict__ z, const float* __restrict__ H,
                            const float* __restrict__ w,
                            float* __restrict__ q, float* __restrict__ kb,
                            float* __restrict__ vb) {
    int wv = threadIdx.x >> 6, l = threadIdx.x & 63;
    int b = blockIdx.x * 4 + wv;
    __shared__ float r[4][64];
    if (b < T_) {
        r[wv][l] = z[b*64+l];
        __syncthreads();
        float s = 0.f;
        #pragma unroll
        for (int j = 0; j < 64; ++j) s += r[wv][j] * w[l*64+j];
        q[b*64+l] = s;
    } else {
        int n = b - T_;
        r[wv][l] = H[n*64+l];
        __syncthreads();
        float sk = 0.f, sv = 0.f;
        #pragma unroll
        for (int j = 0; j < 64; ++j) {
            float hv = r[wv][j];
            sk += hv * w[(64+l)*64+j];
            sv += hv * w[(128+l)*64+j];
        }
        kb[n*64+l] = sk;
        vb[n*64+l] = sv;
    }
}

// ---------------- attention partials: block = (h, chunk, t-group), 4 waves split n ----------------
__global__ void attn_part_kernel(const float* __restrict__ q, const float* __restrict__ kb,
                                 const float* __restrict__ vb,
                                 float* __restrict__ ps, float* __restrict__ pa) {
    int w = threadIdx.x >> 6, lane = threadIdx.x & 63;
    int bid = blockIdx.x;                 // (h*16 + c)*32 + tg
    int tg = bid & 31;
    int c  = (bid >> 5) & 15;
    int h  = bid >> 9;
    int t = tg*64 + lane;
    __shared__ float red[4][64][17];
    float qv[16];
    #pragma unroll
    for (int d = 0; d < 16; ++d) qv[d] = q[t*64 + h*16 + d];
    float ssum = 0.f;
    float acc[16];
    #pragma unroll
    for (int d = 0; d < 16; ++d) acc[d] = 0.f;
    for (int i = 0; i < 16; ++i) {
        int n = c*64 + w*16 + i;
        const float* kr = kb + n*64 + h*16;
        const float* vr = vb + n*64 + h*16;
        float s = 0.f;
        #pragma unroll
        for (int d = 0; d < 16; ++d) s += qv[d] * kr[d];
        float wt = __expf(s * 0.25f);
        ssum += wt;
        #pragma unroll
        for (int d = 0; d < 16; ++d) acc[d] += wt * vr[d];
    }
    #pragma unroll
    for (int d = 0; d < 16; ++d) red[w][lane][d] = acc[d];
    red[w][lane][16] = ssum;
    __syncthreads();
    int tt = threadIdx.x & 63, dq = threadIdx.x >> 6;
    float r0=0.f, r1=0.f, r2=0.f, r3=0.f, sv=0.f;
    #pragma unroll
    for (int ww = 0; ww < 4; ++ww) {
        r0 += red[ww][tt][dq*4+0];
        r1 += red[ww][tt][dq*4+1];
        r2 += red[ww][tt][dq*4+2];
        r3 += red[ww][tt][dq*4+3];
        sv += red[ww][tt][16];
    }
    int idx = (h*NCH + c)*T_ + tg*64 + tt;
    f32x4 vvv = {r0, r1, r2, r3};
    *(f32x4*)&pa[idx*16 + dq*4] = vvv;
    if (dq == 3) ps[idx] = sv;
}

// ---------------- combine partials + out-proj + residual + LN (4 t per block) ----------------
__global__ void attn_fin_kernel(const float* __restrict__ ps, const float* __restrict__ pa,
                                const float* __restrict__ Wout, const float* __restrict__ z,
                                const float* __restrict__ g, const float* __restrict__ bt,
                                float* __restrict__ xout) {
    int w = threadIdx.x >> 6, l = threadIdx.x & 63;
    int t = blockIdx.x * 4 + w;
    int h = l >> 4, d = l & 15;
    __shared__ float osh[4][64];
    float stot = 0.f, atot = 0.f;
    #pragma unroll
    for (int c = 0; c < NCH; ++c) {
        int idx = (h*NCH + c)*T_ + t;
        stot += ps[idx];
        atot += pa[idx*16 + d];
    }
    osh[w][l] = atot / stot;
    __syncthreads();
    float s = 0.f;
    #pragma unroll
    for (int k = 0; k < 64; ++k) s += osh[w][k] * Wout[l*64+k];
    s += z[t*64+l];
    float s1 = s, s2 = s*s;
    #pragma unroll
    for (int m = 32; m >= 1; m >>= 1) { s1 += __shfl_xor(s1, m); s2 += __shfl_xor(s2, m); }
    float mean = s1 * (1.f/64.f);
    float var = s2 * (1.f/64.f) - mean*mean;
    xout[t*64+l] = (s - mean) * rsqrtf(var + 1e-5f) * g[l] + bt[l];
}

// ---------------- FFN + residual + LN ----------------
__global__ void ffn_kernel(const float* __restrict__ x, const float* __restrict__ W1,
                           const float* __restrict__ b1, const float* __restrict__ W2,
                           const float* __restrict__ b2, const float* __restrict__ g,
                           const float* __restrict__ bt, float* __restrict__ zout) {
    int t = blockIdx.x, j = threadIdx.x;
    __shared__ float xr[64];
    __shared__ float h[256];
    if (j < 64) xr[j] = x[t*64+j];
    __syncthreads();
    float s = b1[j];
    #pragma unroll
    for (int k = 0; k < 64; ++k) s += xr[k] * W1[j*64+k];
    h[j] = gelu_f(s);
    __syncthreads();
    if (j < 64) {
        float v = b2[j];
        #pragma unroll
        for (int k = 0; k < 256; ++k) v += h[k] * W2[j*256+k];
        v += xr[j];
        float s1 = v, s2 = v*v;
        #pragma unroll
        for (int m = 32; m >= 1; m >>= 1) { s1 += __shfl_xor(s1, m); s2 += __shfl_xor(s2, m); }
        float mean = s1 * (1.f/64.f);
        float var = s2 * (1.f/64.f) - mean*mean;
        zout[t*64+j] = (v - mean) * rsqrtf(var + 1e-5f) * g[j] + bt[j];
    }
}

// ---------------- az / aH projections (4 rows per block) ----------------
__global__ void azah_kernel(const float* __restrict__ z, const float* __restrict__ H,
                            const float* __restrict__ pw1,
                            float* __restrict__ az, float* __restrict__ aH) {
    int wv = threadIdx.x >> 6, l = threadIdx.x & 63;
    int b = blockIdx.x * 4 + wv;
    __shared__ float r[4][64];
    if (b < T_) {
        r[wv][l] = z[b*64+l];
        __syncthreads();
        float s = 0.f;
        #pragma unroll
        for (int k = 0; k < 64; ++k) s += r[wv][k] * pw1[l*128 + k];
        az[b*64+l] = s;
    } else {
        int n = b - T_;
        r[wv][l] = H[n*64+l];
        __syncthreads();
        float s = 0.f;
        #pragma unroll
        for (int k = 0; k < 64; ++k) s += r[wv][k] * pw1[l*128 + 64 + k];
        aH[n*64+l] = s;
    }
}

// ---------------- fused pairwise head ----------------
// block = 4 t's (one per wave) x one n-quarter (16 tiles of 16 n).
// aH tile staged in LDS (XOR-swizzled, double-buffered, issue-early/write-late).
// Per tile: u=gelu(az+aH+b1) in MFMA-A layout, LN via shfl_xor(16,32),
// 64x64 GEMM via 8x mfma_f32_16x16x32_bf16, gelu, W3 dot + 16-lane reduce,
// result gathered in LDS and stored as one contiguous 192B write per wave.
__global__ void pair_kernel(const float* __restrict__ az, const float* __restrict__ aH,
                            const float* __restrict__ b1, const float* __restrict__ lng,
                            const float* __restrict__ lnb, const float* __restrict__ W2,
                            const float* __restrict__ b2, const float* __restrict__ W3,
                            const float* __restrict__ b3, float* __restrict__ out) {
    int w = threadIdx.x >> 6, lane = threadIdx.x & 63;
    int t = (blockIdx.x >> 2) * 4 + w;
    int qd = blockIdx.x & 3;          // tiles qd*16 .. qd*16+15
    int cLo = lane & 15, kg = lane >> 4;

    __shared__ __align__(16) float buf[2][1024];
    __shared__ float osh[4][48];

    // B fragments of W2 (v_c = sum_k u_k * W2[c,k] => B[k][c] = W2[c*64+k])
    bf16x8 bf[4][2];
    #pragma unroll
    for (int ct = 0; ct < 4; ++ct)
        #pragma unroll
        for (int kt = 0; kt < 2; ++kt) {
            int col = ct*16 + cLo;
            int kbs = kt*32 + kg*8;
            #pragma unroll
            for (int j = 0; j < 8; ++j)
                bf[ct][kt][j] = (__bf16)W2[col*64 + kbs + j];
        }
    float w30[4], w31[4], w32[4], b2v[4];
    #pragma unroll
    for (int ct = 0; ct < 4; ++ct) {
        b2v[ct] = b2[ct*16 + cLo];
        w30[ct] = W3[0*64 + ct*16 + cLo];
        w31[ct] = W3[1*64 + ct*16 + cLo];
        w32[ct] = W3[2*64 + ct*16 + cLo];
    }
    float b30 = b3[0], b31 = b3[1], b32 = b3[2];

    // per-lane dims: d = kt*32 + kg*8 + j
    float azc[16], gv[16], bv[16];
    #pragma unroll
    for (int kt = 0; kt < 2; ++kt)
        #pragma unroll
        for (int j = 0; j < 8; ++j) {
            int d = kt*32 + kg*8 + j;
            azc[kt*8+j] = az[t*64 + d] + b1[d];
            gv[kt*8+j]  = lng[d];
            bv[kt*8+j]  = lnb[d];
        }

    // staging geometry: thread i stages 16B; LDS dword i*4 holds
    // (row=i>>4, logical col = ((i&15)*4) ^ ((row&7)<<2)) .. +3
    int si = threadIdx.x;
    int srow = si >> 4;
    int scol = ((si & 15) << 2) ^ ((srow & 7) << 2);
    const float* srcBase = aH + srow*64 + scol;
    int swzR = (cLo & 7) << 2;

    // prologue: stage tile qd*16
    {
        f32x4 v = *(const f32x4*)(srcBase + (qd*16)*1024);
        *(f32x4*)&buf[0][si*4] = v;
    }
    __syncthreads();

    for (int k = 0; k < 16; ++k) {
        int tile = qd*16 + k;
        f32x4 pre;
        if (k < 15) pre = *(const f32x4*)(srcBase + (tile+1)*1024);

        const float* B = buf[k & 1];
        float u[16];
        float s1 = 0.f, s2 = 0.f;
        #pragma unroll
        for (int kt = 0; kt < 2; ++kt) {
            int cb = kt*32 + kg*8;
            f32x4 a0 = *(const f32x4*)&B[cLo*64 + (cb ^ swzR)];
            f32x4 a1 = *(const f32x4*)&B[cLo*64 + ((cb+4) ^ swzR)];
            #pragma unroll
            for (int j = 0; j < 4; ++j) {
                float uu = gelu_f(azc[kt*8+j] + a0[j]);
                u[kt*8+j] = uu; s1 += uu; s2 += uu*uu;
            }
            #pragma unroll
            for (int j = 0; j < 4; ++j) {
                float uu = gelu_f(azc[kt*8+4+j] + a1[j]);
                u[kt*8+4+j] = uu; s1 += uu; s2 += uu*uu;
            }
        }
        s1 += __shfl_xor(s1, 16); s1 += __shfl_xor(s1, 32);
        s2 += __shfl_xor(s2, 16); s2 += __shfl_xor(s2, 32);
        float mean = s1 * (1.0f/64.0f);
        float var = s2 * (1.0f/64.0f) - mean*mean;
        float inv = rsqrtf(var + 1e-5f);

        bf16x8 af[2];
        #pragma unroll
        for (int kt = 0; kt < 2; ++kt)
            #pragma unroll
            for (int j = 0; j < 8; ++j)
                af[kt][j] = (__bf16)((u[kt*8+j] - mean) * inv * gv[kt*8+j] + bv[kt*8+j]);

        f32x4 acc[4];
        #pragma unroll
        for (int ct = 0; ct < 4; ++ct) acc[ct] = (f32x4){0.f,0.f,0.f,0.f};
        #pragma unroll
        for (int ct = 0; ct < 4; ++ct)
            #pragma unroll
            for (int kt = 0; kt < 2; ++kt)
                acc[ct] = __builtin_amdgcn_mfma_f32_16x16x32_bf16(af[kt], bf[ct][kt], acc[ct], 0, 0, 0);

        float p0[4] = {0,0,0,0}, p1[4] = {0,0,0,0}, p2[4] = {0,0,0,0};
        #pragma unroll
        for (int ct = 0; ct < 4; ++ct)
            #pragma unroll
            for (int r = 0; r < 4; ++r) {
                float vg = gelu_f(acc[ct][r] + b2v[ct]);
                p0[r] += vg * w30[ct];
                p1[r] += vg * w31[ct];
                p2[r] += vg * w32[ct];
            }
        #pragma unroll
        for (int r = 0; r < 4; ++r) {
            p0[r] += __shfl_xor(p0[r], 1); p0[r] += __shfl_xor(p0[r], 2);
            p0[r] += __shfl_xor(p0[r], 4); p0[r] += __shfl_xor(p0[r], 8);
            p1[r] += __shfl_xor(p1[r], 1); p1[r] += __shfl_xor(p1[r], 2);
            p1[r] += __shfl_xor(p1[r], 4); p1[r] += __shfl_xor(p1[r], 8);
            p2[r] += __shfl_xor(p2[r], 1); p2[r] += __shfl_xor(p2[r], 2);
            p2[r] += __shfl_xor(p2[r], 4); p2[r] += __shfl_xor(p2[r], 8);
        }
        if (cLo < 3) {
            #pragma unroll
            for (int r = 0; r < 4; ++r) {
                float vv = (cLo == 0) ? p0[r] : (cLo == 1 ? p1[r] : p2[r]);
                float bb = (cLo == 0) ? b30 : (cLo == 1 ? b31 : b32);
                osh[w][(kg*4 + r)*3 + cLo] = vv + bb;
            }
        }
        __builtin_amdgcn_wave_barrier();
        if (lane < 48) out[t*3072 + tile*48 + lane] = osh[w][lane];

        if (k < 15) *(f32x4*)&buf[(k+1) & 1][si*4] = pre;
        __syncthreads();
    }
}

extern "C" void kernel_launch(void* const* d_in, const int* in_sizes, int n_in,
                              void* d_out, int out_size, void* d_ws, size_t ws_size,
                              hipStream_t stream) {
    const float* H         = (const float*)d_in[0];
    const float* qpts      = (const float*)d_in[1];
    const float* qe_W1     = (const float*)d_in[2];
    const float* qe_b1     = (const float*)d_in[3];
    const float* qe_W2     = (const float*)d_in[4];
    const float* qe_b2     = (const float*)d_in[5];
    const float* attn_in_w = (const float*)d_in[6];
    const float* attn_out_w= (const float*)d_in[7];
    const float* ln1_g     = (const float*)d_in[8];
    const float* ln1_b     = (const float*)d_in[9];
    const float* ffn_W1    = (const float*)d_in[10];
    const float* ffn_b1    = (const float*)d_in[11];
    const float* ffn_W2    = (const float*)d_in[12];
    const float* ffn_b2    = (const float*)d_in[13];
    const float* ln2_g     = (const float*)d_in[14];
    const float* ln2_b     = (const float*)d_in[15];
    const float* pm_W1     = (const float*)d_in[16];
    const float* pm_b1     = (const float*)d_in[17];
    const float* pm_ln_g   = (const float*)d_in[18];
    const float* pm_ln_b   = (const float*)d_in[19];
    const float* pm_W2     = (const float*)d_in[20];
    const float* pm_b2     = (const float*)d_in[21];
    const float* pm_W3     = (const float*)d_in[22];
    const float* pm_b3     = (const float*)d_in[23];

    float* ws = (float*)d_ws;
    float* z  = ws;            // 131072
    float* xb = ws + 131072;   // 131072
    float* q  = ws + 262144;   // 131072
    float* kb = ws + 393216;   // 65536
    float* vb = ws + 458752;   // 65536
    float* az = ws + 524288;   // 131072
    float* aH = ws + 655360;   // 65536
    float* ps = ws + 720896;   // 4*16*2048 = 131072
    float* pa = ws + 851968;   // 131072*16 = 2097152
    float* out = (float*)d_out;

    qe_kernel<<<T_/4, 256, 0, stream>>>(qpts, qe_W1, qe_b1, qe_W2, qe_b2, z);
    for (int i = 0; i < 2; ++i) {
        proj_kernel<<<(T_+N_)/4, 256, 0, stream>>>(z, H, attn_in_w + i*192*64, q, kb, vb);
        attn_part_kernel<<<2048, 256, 0, stream>>>(q, kb, vb, ps, pa);
        attn_fin_kernel<<<T_/4, 256, 0, stream>>>(ps, pa, attn_out_w + i*64*64, z,
                                                  ln1_g + i*64, ln1_b + i*64, xb);
        ffn_kernel<<<T_, 256, 0, stream>>>(xb, ffn_W1 + i*256*64, ffn_b1 + i*256,
                                           ffn_W2 + i*64*256, ffn_b2 + i*64,
                                           ln2_g + i*64, ln2_b + i*64, z);
    }
    azah_kernel<<<(T_+N_)/4, 256, 0, stream>>>(z, H, pm_W1, az, aH);
    pair_kernel<<<2048, 256, 0, stream>>>(az, aH, pm_b1, pm_ln_g, pm_ln_b,
                                          pm_W2, pm_b2, pm_W3, pm_b3, out);
}

// Round 3
// 325.449 us; speedup vs baseline: 1.6290x; 1.3588x over previous
//
#include <hip/hip_runtime.h>
#include <hip/hip_bf16.h>

#define T_ 2048
#define N_ 1024
#define NCH 16

typedef __bf16 bf16x8 __attribute__((ext_vector_type(8)));
typedef _Float16 f16x4 __attribute__((ext_vector_type(4)));
typedef float f32x4 __attribute__((ext_vector_type(4)));

__device__ __forceinline__ float gelu_f(float x) {
    // Phi via A&S 7.1.25 erfc (3-term), |erf err| <= 2.5e-5
    float s = x * 0.7071067811865476f;
    float a = fabsf(s);
    float t = __builtin_amdgcn_rcpf(fmaf(0.47047f, a, 1.0f));
    float poly = t * fmaf(t, fmaf(t, 0.3739278f, -0.0479399f), 0.1740121f);
    float e = __expf(-a * a);
    float hq = poly * e;                  // 0.5*erfc(a)
    float phi = (x >= 0.0f) ? (1.0f - hq) : hq;
    return x * phi;
}

// ---------------- query embedding (4 t per block, 1 per wave) ----------------
__global__ void qe_kernel(const float* __restrict__ qpts, const float* __restrict__ W1,
                          const float* __restrict__ b1, const float* __restrict__ W2,
                          const float* __restrict__ b2, float* __restrict__ z) {
    int w = threadIdx.x >> 6, l = threadIdx.x & 63;
    int t = blockIdx.x * 4 + w;
    __shared__ float inp[4][52];
    __shared__ float h[4][64];
    float q0 = qpts[t*3+0], q1 = qpts[t*3+1], q2 = qpts[t*3+2];
    if (l < 3) inp[w][l] = (l==0?q0:(l==1?q1:q2));
    if (l < 48) {
        int i = l >> 4, r = l & 15, f = r & 7;
        float qv = (i==0?q0:(i==1?q1:q2));
        float ang = qv * ((float)(1<<f) * 3.14159265358979323846f);
        inp[w][3+l] = (r < 8) ? sinf(ang) : cosf(ang);
    }
    __syncthreads();
    float s = b1[l];
    #pragma unroll
    for (int j = 0; j < 51; ++j) s += inp[w][j] * W1[l*51+j];
    h[w][l] = gelu_f(s);
    __syncthreads();
    float s2 = b2[l];
    #pragma unroll
    for (int k = 0; k < 64; ++k) s2 += h[w][k] * W2[l*64+k];
    z[t*64+l] = s2;
}

// ---------------- q/k/v projections (4 rows per block) ----------------
__global__ void proj_kernel(const float* __restrict__ z, const float* __restrict__ H,
                            const float* __restrict__ w,
                            float* __restrict__ q, float* __restrict__ kb,
                            float* __restrict__ vb) {
    int wv = threadIdx.x >> 6, l = threadIdx.x & 63;
    int b = blockIdx.x * 4 + wv;
    __shared__ float r[4][64];
    if (b < T_) {
        r[wv][l] = z[b*64+l];
        __syncthreads();
        float s = 0.f;
        #pragma unroll
        for (int j = 0; j < 64; ++j) s += r[wv][j] * w[l*64+j];
        q[b*64+l] = s;
    } else {
        int n = b - T_;
        r[wv][l] = H[n*64+l];
        __syncthreads();
        float sk = 0.f, sv = 0.f;
        #pragma unroll
        for (int j = 0; j < 64; ++j) {
            float hv = r[wv][j];
            sk += hv * w[(64+l)*64+j];
            sv += hv * w[(128+l)*64+j];
        }
        kb[n*64+l] = sk;
        vb[n*64+l] = sv;
    }
}

// ---------------- attention partials: block = (h, chunk, t-group), 4 waves split n ----------------
__global__ void attn_part_kernel(const float* __restrict__ q, const float* __restrict__ kb,
                                 const float* __restrict__ vb,
                                 float* __restrict__ ps, float* __restrict__ pa) {
    int w = threadIdx.x >> 6, lane = threadIdx.x & 63;
    int bid = blockIdx.x;                 // (h*16 + c)*32 + tg
    int tg = bid & 31;
    int c  = (bid >> 5) & 15;
    int h  = bid >> 9;
    int t = tg*64 + lane;
    __shared__ float red[4][64][17];
    float qv[16];
    #pragma unroll
    for (int d = 0; d < 16; ++d) qv[d] = q[t*64 + h*16 + d];
    float ssum = 0.f;
    float acc[16];
    #pragma unroll
    for (int d = 0; d < 16; ++d) acc[d] = 0.f;
    for (int i = 0; i < 16; ++i) {
        int n = c*64 + w*16 + i;
        const float* kr = kb + n*64 + h*16;
        const float* vr = vb + n*64 + h*16;
        float s = 0.f;
        #pragma unroll
        for (int d = 0; d < 16; ++d) s += qv[d] * kr[d];
        float wt = __expf(s * 0.25f);
        ssum += wt;
        #pragma unroll
        for (int d = 0; d < 16; ++d) acc[d] += wt * vr[d];
    }
    #pragma unroll
    for (int d = 0; d < 16; ++d) red[w][lane][d] = acc[d];
    red[w][lane][16] = ssum;
    __syncthreads();
    int tt = threadIdx.x & 63, dq = threadIdx.x >> 6;
    float r0=0.f, r1=0.f, r2=0.f, r3=0.f, sv=0.f;
    #pragma unroll
    for (int ww = 0; ww < 4; ++ww) {
        r0 += red[ww][tt][dq*4+0];
        r1 += red[ww][tt][dq*4+1];
        r2 += red[ww][tt][dq*4+2];
        r3 += red[ww][tt][dq*4+3];
        sv += red[ww][tt][16];
    }
    int idx = (h*NCH + c)*T_ + tg*64 + tt;
    f32x4 vvv = {r0, r1, r2, r3};
    *(f32x4*)&pa[idx*16 + dq*4] = vvv;
    if (dq == 3) ps[idx] = sv;
}

// ---------------- combine partials + out-proj + residual + LN (4 t per block) ----------------
__global__ void attn_fin_kernel(const float* __restrict__ ps, const float* __restrict__ pa,
                                const float* __restrict__ Wout, const float* __restrict__ z,
                                const float* __restrict__ g, const float* __restrict__ bt,
                                float* __restrict__ xout) {
    int w = threadIdx.x >> 6, l = threadIdx.x & 63;
    int t = blockIdx.x * 4 + w;
    int h = l >> 4, d = l & 15;
    __shared__ float osh[4][64];
    float stot = 0.f, atot = 0.f;
    #pragma unroll
    for (int c = 0; c < NCH; ++c) {
        int idx = (h*NCH + c)*T_ + t;
        stot += ps[idx];
        atot += pa[idx*16 + d];
    }
    osh[w][l] = atot / stot;
    __syncthreads();
    float s = 0.f;
    #pragma unroll
    for (int k = 0; k < 64; ++k) s += osh[w][k] * Wout[l*64+k];
    s += z[t*64+l];
    float s1 = s, s2 = s*s;
    #pragma unroll
    for (int m = 32; m >= 1; m >>= 1) { s1 += __shfl_xor(s1, m); s2 += __shfl_xor(s2, m); }
    float mean = s1 * (1.f/64.f);
    float var = s2 * (1.f/64.f) - mean*mean;
    xout[t*64+l] = (s - mean) * rsqrtf(var + 1e-5f) * g[l] + bt[l];
}

// ---------------- FFN + residual + LN ----------------
__global__ void ffn_kernel(const float* __restrict__ x, const float* __restrict__ W1,
                           const float* __restrict__ b1, const float* __restrict__ W2,
                           const float* __restrict__ b2, const float* __restrict__ g,
                           const float* __restrict__ bt, float* __restrict__ zout) {
    int t = blockIdx.x, j = threadIdx.x;
    __shared__ float xr[64];
    __shared__ float h[256];
    if (j < 64) xr[j] = x[t*64+j];
    __syncthreads();
    float s = b1[j];
    #pragma unroll
    for (int k = 0; k < 64; ++k) s += xr[k] * W1[j*64+k];
    h[j] = gelu_f(s);
    __syncthreads();
    if (j < 64) {
        float v = b2[j];
        #pragma unroll
        for (int k = 0; k < 256; ++k) v += h[k] * W2[j*256+k];
        v += xr[j];
        float s1 = v, s2 = v*v;
        #pragma unroll
        for (int m = 32; m >= 1; m >>= 1) { s1 += __shfl_xor(s1, m); s2 += __shfl_xor(s2, m); }
        float mean = s1 * (1.f/64.f);
        float var = s2 * (1.f/64.f) - mean*mean;
        zout[t*64+j] = (v - mean) * rsqrtf(var + 1e-5f) * g[j] + bt[j];
    }
}

// ---------------- az / aH projections (4 rows per block) ----------------
__global__ void azah_kernel(const float* __restrict__ z, const float* __restrict__ H,
                            const float* __restrict__ pw1,
                            float* __restrict__ az, float* __restrict__ aH) {
    int wv = threadIdx.x >> 6, l = threadIdx.x & 63;
    int b = blockIdx.x * 4 + wv;
    __shared__ float r[4][64];
    if (b < T_) {
        r[wv][l] = z[b*64+l];
        __syncthreads();
        float s = 0.f;
        #pragma unroll
        for (int k = 0; k < 64; ++k) s += r[wv][k] * pw1[l*128 + k];
        az[b*64+l] = s;
    } else {
        int n = b - T_;
        r[wv][l] = H[n*64+l];
        __syncthreads();
        float s = 0.f;
        #pragma unroll
        for (int k = 0; k < 64; ++k) s += r[wv][k] * pw1[l*128 + 64 + k];
        aH[n*64+l] = s;
    }
}

// ---------------- prep: fold LN affine into W2 ----------------
// W2g[c][d] = W2[c][d]*g[d];  Kg[c] = sum_d g[d]W2[c][d];  Kb[c] = sum_d b[d]W2[c][d] + b2[c]
__global__ void prep_kernel(const float* __restrict__ W2, const float* __restrict__ g,
                            const float* __restrict__ b, const float* __restrict__ b2,
                            __bf16* __restrict__ w2g, float* __restrict__ kgv,
                            float* __restrict__ kbv) {
    int c = threadIdx.x;  // 64 threads
    float sg = 0.f, sb = 0.f;
    #pragma unroll
    for (int d = 0; d < 64; ++d) {
        float wv = W2[c*64 + d];
        float gg = g[d];
        w2g[c*64 + d] = (__bf16)(wv * gg);
        sg = fmaf(wv, gg, sg);
        sb = fmaf(wv, b[d], sb);
    }
    kgv[c] = sg;
    kbv[c] = sb + b2[c];
}

// ---------------- fused pairwise head v3 ----------------
// wave = (t, n-quarter); loops 16 tiles of 16 n. No block-level sync in loop.
// MFMA1: A = W2g (LDS, swizzled), B = u = gelu(az+aH+b1) -> D[c][p] (c in kg*4-blocks).
// LN folded: v = inv*U - (inv*mean)*Kg[c] + Kb[c].  D-layout == B-frag of K=16 MFMA:
// MFMA2: 4x mfma_f32_16x16x16f16(A=W3pad, B=gelu(v)) -> out[j][p], stored by kg==0 lanes
// as 16 x 12B contiguous.
__global__ void __launch_bounds__(256, 3) pair_kernel(
        const float* __restrict__ az, const float* __restrict__ aH,
        const float* __restrict__ b1, const __bf16* __restrict__ w2g,
        const float* __restrict__ kgv, const float* __restrict__ kbv,
        const float* __restrict__ W3, const float* __restrict__ b3,
        float* __restrict__ out) {
    int w = threadIdx.x >> 6, lane = threadIdx.x & 63;
    int wid = blockIdx.x * 4 + w;
    int t = wid >> 2, qd = wid & 3;
    int cLo = lane & 15, kg = lane >> 4;

    // stage W2g (bf16, XOR-swizzled) into LDS: row*128B, byte ^= (row&7)<<4
    __shared__ __align__(16) char w2s[8192];
    {
        int i = threadIdx.x;
        #pragma unroll
        for (int hh = 0; hh < 2; ++hh) {
            int elem = i * 16 + hh * 8;            // bf16 index, 16B chunk
            int row = elem >> 6;
            int colb = (elem & 63) << 1;
            int sw = colb ^ ((row & 7) << 4);
            *(uint4*)(w2s + row * 128 + sw) = *(const uint4*)((const char*)w2g + elem * 2);
        }
    }
    __syncthreads();

    // per-lane constants: d = kt*32+kg*8+j ; c = ct*16+kg*4+r
    float azc[16];
    #pragma unroll
    for (int kt = 0; kt < 2; ++kt)
        #pragma unroll
        for (int hh = 0; hh < 2; ++hh) {
            f32x4 av = *(const f32x4*)&az[t*64 + kt*32 + kg*8 + hh*4];
            f32x4 bv = *(const f32x4*)&b1[kt*32 + kg*8 + hh*4];
            #pragma unroll
            for (int j = 0; j < 4; ++j) azc[kt*8 + hh*4 + j] = av[j] + bv[j];
        }
    float kgc[16], kbc[16];
    #pragma unroll
    for (int ct = 0; ct < 4; ++ct) {
        f32x4 g4 = *(const f32x4*)&kgv[ct*16 + kg*4];
        f32x4 b4 = *(const f32x4*)&kbv[ct*16 + kg*4];
        #pragma unroll
        for (int r = 0; r < 4; ++r) { kgc[ct*4+r] = g4[r]; kbc[ct*4+r] = b4[r]; }
    }
    f16x4 w3f[4];
    #pragma unroll
    for (int ct = 0; ct < 4; ++ct)
        #pragma unroll
        for (int j = 0; j < 4; ++j)
            w3f[ct][j] = (cLo < 3) ? (_Float16)W3[cLo*64 + ct*16 + kg*4 + j] : (_Float16)0.0f;
    float b30 = b3[0], b31 = b3[1], b32v = b3[2];

    const float* aHb = aH + (qd*256 + cLo) * 64 + kg * 8;
    int swz = (cLo & 7) << 4;
    const char* wrow0 = w2s + cLo * 128;

    auto LOADTILE = [&](f32x4* buf, int k) {
        const float* p = aHb + k * 1024;
        buf[0] = *(const f32x4*)(p);
        buf[1] = *(const f32x4*)(p + 4);
        buf[2] = *(const f32x4*)(p + 32);
        buf[3] = *(const f32x4*)(p + 36);
    };

    auto BODY = [&](const f32x4* buf, int tile) {
        float u[16], s1 = 0.f, s2 = 0.f;
        #pragma unroll
        for (int kt = 0; kt < 2; ++kt)
            #pragma unroll
            for (int hh = 0; hh < 2; ++hh) {
                f32x4 vv = buf[kt*2+hh];
                #pragma unroll
                for (int j = 0; j < 4; ++j) {
                    float uu = gelu_f(azc[kt*8 + hh*4 + j] + vv[j]);
                    u[kt*8 + hh*4 + j] = uu; s1 += uu; s2 = fmaf(uu, uu, s2);
                }
            }
        s1 += __shfl_xor(s1, 16); s1 += __shfl_xor(s1, 32);
        s2 += __shfl_xor(s2, 16); s2 += __shfl_xor(s2, 32);
        float mean = s1 * 0.015625f;
        float var  = fmaf(s2, 0.015625f, -mean * mean);
        float inv  = rsqrtf(var + 1e-5f);
        float im   = inv * mean;

        bf16x8 uf[2];
        #pragma unroll
        for (int kt = 0; kt < 2; ++kt)
            #pragma unroll
            for (int j = 0; j < 8; ++j) uf[kt][j] = (__bf16)u[kt*8 + j];

        f32x4 acc[4];
        #pragma unroll
        for (int ct = 0; ct < 4; ++ct) acc[ct] = (f32x4){0.f, 0.f, 0.f, 0.f};
        #pragma unroll
        for (int ct = 0; ct < 4; ++ct) {
            const char* wr = wrow0 + ct * 2048;
            #pragma unroll
            for (int kt = 0; kt < 2; ++kt) {
                bf16x8 wfr = *(const bf16x8*)(wr + ((kt*64 + kg*16) ^ swz));
                acc[ct] = __builtin_amdgcn_mfma_f32_16x16x32_bf16(wfr, uf[kt], acc[ct], 0, 0, 0);
            }
        }
        f16x4 vgf[4];
        #pragma unroll
        for (int ct = 0; ct < 4; ++ct)
            #pragma unroll
            for (int r = 0; r < 4; ++r) {
                float v = fmaf(inv, acc[ct][r], fmaf(-im, kgc[ct*4+r], kbc[ct*4+r]));
                vgf[ct][r] = (_Float16)gelu_f(v);
            }
        f32x4 acc2 = (f32x4){0.f, 0.f, 0.f, 0.f};
        #pragma unroll
        for (int ct = 0; ct < 4; ++ct)
            acc2 = __builtin_amdgcn_mfma_f32_16x16x16f16(w3f[ct], vgf[ct], acc2, 0, 0, 0);
        if (kg == 0) {
            float* op = out + t*3072 + (tile*16 + cLo)*3;
            op[0] = acc2[0] + b30;
            op[1] = acc2[1] + b31;
            op[2] = acc2[2] + b32v;
        }
    };

    f32x4 bufA[4], bufB[4];
    LOADTILE(bufA, 0);
    #pragma unroll 1
    for (int k = 0; k < 16; k += 2) {
        LOADTILE(bufB, k + 1);
        BODY(bufA, qd*16 + k);
        if (k + 2 < 16) LOADTILE(bufA, k + 2);
        BODY(bufB, qd*16 + k + 1);
    }
}

extern "C" void kernel_launch(void* const* d_in, const int* in_sizes, int n_in,
                              void* d_out, int out_size, void* d_ws, size_t ws_size,
                              hipStream_t stream) {
    const float* H         = (const float*)d_in[0];
    const float* qpts      = (const float*)d_in[1];
    const float* qe_W1     = (const float*)d_in[2];
    const float* qe_b1     = (const float*)d_in[3];
    const float* qe_W2     = (const float*)d_in[4];
    const float* qe_b2     = (const float*)d_in[5];
    const float* attn_in_w = (const float*)d_in[6];
    const float* attn_out_w= (const float*)d_in[7];
    const float* ln1_g     = (const float*)d_in[8];
    const float* ln1_b     = (const float*)d_in[9];
    const float* ffn_W1    = (const float*)d_in[10];
    const float* ffn_b1    = (const float*)d_in[11];
    const float* ffn_W2    = (const float*)d_in[12];
    const float* ffn_b2    = (const float*)d_in[13];
    const float* ln2_g     = (const float*)d_in[14];
    const float* ln2_b     = (const float*)d_in[15];
    const float* pm_W1     = (const float*)d_in[16];
    const float* pm_b1     = (const float*)d_in[17];
    const float* pm_ln_g   = (const float*)d_in[18];
    const float* pm_ln_b   = (const float*)d_in[19];
    const float* pm_W2     = (const float*)d_in[20];
    const float* pm_b2     = (const float*)d_in[21];
    const float* pm_W3     = (const float*)d_in[22];
    const float* pm_b3     = (const float*)d_in[23];

    float* ws = (float*)d_ws;
    float* z  = ws;            // 131072
    float* xb = ws + 131072;   // 131072
    float* q  = ws + 262144;   // 131072
    float* kb = ws + 393216;   // 65536
    float* vb = ws + 458752;   // 65536
    float* az = ws + 524288;   // 131072
    float* aH = ws + 655360;   // 65536
    float* ps = ws + 720896;   // 131072
    float* pa = ws + 851968;   // 2097152  (end 2949120)
    __bf16* w2g = (__bf16*)(ws + 2949120);   // 4096 bf16 = 2048 f32 slots
    float* kgv = ws + 2951168; // 64
    float* kbv = ws + 2951232; // 64       (end 2951296 floats ~ 11.8 MB)
    float* out = (float*)d_out;

    qe_kernel<<<T_/4, 256, 0, stream>>>(qpts, qe_W1, qe_b1, qe_W2, qe_b2, z);
    for (int i = 0; i < 2; ++i) {
        proj_kernel<<<(T_+N_)/4, 256, 0, stream>>>(z, H, attn_in_w + i*192*64, q, kb, vb);
        attn_part_kernel<<<2048, 256, 0, stream>>>(q, kb, vb, ps, pa);
        attn_fin_kernel<<<T_/4, 256, 0, stream>>>(ps, pa, attn_out_w + i*64*64, z,
                                                  ln1_g + i*64, ln1_b + i*64, xb);
        ffn_kernel<<<T_, 256, 0, stream>>>(xb, ffn_W1 + i*256*64, ffn_b1 + i*256,
                                           ffn_W2 + i*64*256, ffn_b2 + i*64,
                                           ln2_g + i*64, ln2_b + i*64, z);
    }
    azah_kernel<<<(T_+N_)/4, 256, 0, stream>>>(z, H, pm_W1, az, aH);
    prep_kernel<<<1, 64, 0, stream>>>(pm_W2, pm_ln_g, pm_ln_b, pm_b2, w2g, kgv, kbv);
    pair_kernel<<<2048, 256, 0, stream>>>(az, aH, pm_b1, w2g, kgv, kbv,
                                          pm_W3, pm_b3, out);
}